// Round 2
// baseline (439.707 us; speedup 1.0000x reference)
//
#include <hip/hip_runtime.h>

typedef __attribute__((ext_vector_type(4))) float fvec4;

// low:   [N=4][C=64][H=256][W=256] f32
// highs: [N][C][3][H][W] f32  (planes: lh, hl, hh)
// out:   [N][C][512][512] f32
// Inverse DWT (L=2 synthesis): every output 2x2 quad is a 4-input butterfly:
//   y[2m+dr][2n+dc] = (low*g0c[dr] + lh*g1c[dr])*g0r[dc]
//                   + (hl*g0c[dr] + hh*g1c[dr])*g1r[dc]
// One thread handles 4 input columns of one (nc, m): 4x16B loads, 4x16B stores.
__global__ __launch_bounds__(256) void idwt2_kernel(
    const float* __restrict__ low,
    const float* __restrict__ highs,
    const float* __restrict__ g0c, const float* __restrict__ g1c,
    const float* __restrict__ g0r, const float* __restrict__ g1r,
    float* __restrict__ out)
{
    const int tid = blockIdx.x * 256 + threadIdx.x;
    const int wg = tid & 63;          // column group (4 input cols each)
    const int m  = (tid >> 6) & 255;  // input row
    const int nc = tid >> 14;         // n*C + c, 0..255

    // synthesis filter taps (wave-uniform scalar loads)
    const float a0 = g0c[0], a1 = g0c[1];   // g0_col
    const float b0 = g1c[0], b1 = g1c[1];   // g1_col
    const float p0 = g0r[0], p1 = g0r[1];   // g0_row
    const float q0 = g1r[0], q1 = g1r[1];   // g1_row

    const size_t plane  = 65536;                                   // 256*256
    const size_t in_off = (size_t)nc * plane + (size_t)m * 256 + (size_t)(wg * 4);
    const size_t h_off  = (size_t)nc * 3 * plane + (size_t)m * 256 + (size_t)(wg * 4);

    const fvec4 vl  = *(const fvec4*)(low   + in_off);
    const fvec4 vlh = *(const fvec4*)(highs + h_off);
    const fvec4 vhl = *(const fvec4*)(highs + h_off + plane);
    const fvec4 vhh = *(const fvec4*)(highs + h_off + 2 * plane);

    // output: rows 2m, 2m+1; cols [8*wg, 8*wg+8)
    const size_t orow0 = ((size_t)nc * 512 + (size_t)(2 * m)) * 512 + (size_t)(wg * 8);

    #pragma unroll
    for (int dr = 0; dr < 2; ++dr) {
        const float a = dr ? a1 : a0;   // g0_col[dr]
        const float b = dr ? b1 : b0;   // g1_col[dr]
        fvec4 o0, o1;
        #pragma unroll
        for (int j = 0; j < 4; ++j) {
            const float lov = vl[j]  * a + vlh[j] * b;  // col-pass lo branch
            const float hiv = vhl[j] * a + vhh[j] * b;  // col-pass hi branch
            const float ev  = lov * p0 + hiv * q0;      // out col 2j
            const float od  = lov * p1 + hiv * q1;      // out col 2j+1
            if (j < 2) { o0[2 * j]       = ev; o0[2 * j + 1]       = od; }
            else       { o1[2 * (j - 2)] = ev; o1[2 * (j - 2) + 1] = od; }
        }
        *(fvec4*)(out + orow0 + (size_t)dr * 512)     = o0;
        *(fvec4*)(out + orow0 + (size_t)dr * 512 + 4) = o1;
    }
}

extern "C" void kernel_launch(void* const* d_in, const int* in_sizes, int n_in,
                              void* d_out, int out_size, void* d_ws, size_t ws_size,
                              hipStream_t stream) {
    const float* low   = (const float*)d_in[0];
    const float* highs = (const float*)d_in[1];
    const float* g0c   = (const float*)d_in[2];
    const float* g1c   = (const float*)d_in[3];
    const float* g0r   = (const float*)d_in[4];
    const float* g1r   = (const float*)d_in[5];
    float* out = (float*)d_out;

    // total threads = N*C*H*(W/4) = 4*64*256*64 = 4,194,304 -> 16384 blocks
    idwt2_kernel<<<dim3(16384), dim3(256), 0, stream>>>(low, highs, g0c, g1c, g0r, g1r, out);
}